// Round 3
// baseline (16868.716 us; speedup 1.0000x reference)
//
#include <hip/hip_runtime.h>
#include <cstdint>
#include <cstddef>

#define HHEADS 16
#define DHEAD  64
#define NSEQ   2048
#define NBATCH 2
#define NDIM   1024
#define TOPKN  64
#define CAP    68
#define NROWS  (NBATCH*HHEADS*NSEQ)   // 65536

// ---------------------------------------------------------------------------
// Kernel 1: QKV GEMM.  x[4096,1024] @ Wqkv[1024,3072] + bqkv
// -> q,k,v each laid out [B,H,N,DH]
// ---------------------------------------------------------------------------
__global__ __launch_bounds__(256) void qkv_gemm(
    const float* __restrict__ x, const float* __restrict__ W,
    const float* __restrict__ bias,
    float* __restrict__ qout, float* __restrict__ kout, float* __restrict__ vout)
{
    __shared__ float As[16][64];   // transposed A tile
    __shared__ float Bs[16][64];
    const int tid = threadIdx.x;
    const int rowBase = blockIdx.y * 64;
    const int colBase = blockIdx.x * 64;
    const int tx = tid & 15, ty = tid >> 4;
    const int aRow = tid >> 2, aCol = (tid & 3) << 2;
    const int bRow = tid >> 4, bCol = (tid & 15) << 2;

    float acc[4][4] = {};
    for (int k0 = 0; k0 < NDIM; k0 += 16) {
        float4 av = *reinterpret_cast<const float4*>(&x[(size_t)(rowBase + aRow) * NDIM + k0 + aCol]);
        float4 bv = *reinterpret_cast<const float4*>(&W[(size_t)(k0 + bRow) * 3072 + colBase + bCol]);
        __syncthreads();
        As[aCol + 0][aRow] = av.x; As[aCol + 1][aRow] = av.y;
        As[aCol + 2][aRow] = av.z; As[aCol + 3][aRow] = av.w;
        *reinterpret_cast<float4*>(&Bs[bRow][bCol]) = bv;
        __syncthreads();
#pragma unroll
        for (int kk = 0; kk < 16; kk++) {
            float4 a4 = *reinterpret_cast<const float4*>(&As[kk][ty << 2]);
            float4 b4 = *reinterpret_cast<const float4*>(&Bs[kk][tx << 2]);
            float ar[4] = {a4.x, a4.y, a4.z, a4.w};
            float br[4] = {b4.x, b4.y, b4.z, b4.w};
#pragma unroll
            for (int i = 0; i < 4; i++)
#pragma unroll
                for (int j = 0; j < 4; j++) acc[i][j] += ar[i] * br[j];
        }
    }
    const int which = colBase >> 10;
    const int h = (colBase & 1023) >> 6;
    float* dst = which == 0 ? qout : (which == 1 ? kout : vout);
    const int d0 = (colBase + (tx << 2)) & 63;
    float4 bb = *reinterpret_cast<const float4*>(&bias[colBase + (tx << 2)]);
#pragma unroll
    for (int i = 0; i < 4; i++) {
        int r = rowBase + (ty << 2) + i;
        int b = r >> 11, n = r & 2047;
        size_t o = ((size_t)((b << 4) + h) * NSEQ + n) * DHEAD + d0;
        float4 st;
        st.x = acc[i][0] + bb.x; st.y = acc[i][1] + bb.y;
        st.z = acc[i][2] + bb.z; st.w = acc[i][3] + bb.w;
        *reinterpret_cast<float4*>(&dst[o]) = st;
    }
}

// ---------------------------------------------------------------------------
// order-preserving float<->uint key transforms
// ---------------------------------------------------------------------------
__device__ __forceinline__ uint32_t f2key(float f) {
    uint32_t u = __float_as_uint(f);
    return (u & 0x80000000u) ? ~u : (u | 0x80000000u);
}
__device__ __forceinline__ float key2f(uint32_t k) {
    uint32_t u = (k & 0x80000000u) ? (k & 0x7FFFFFFFu) : ~k;
    return __uint_as_float(u);
}

// Per-row: exact top-64 (ties kept, like the reference), softmax over kept,
// compacted emit of (key index, prob).  s[t] holds score of key j = t*64+lane.
__device__ __forceinline__ void topk_softmax_emit(
    float (&s)[32], int row, int lane,
    int* __restrict__ tki, float* __restrict__ tkp, int* __restrict__ tkc)
{
    // row max
    float m = -3.4e38f;
#pragma unroll
    for (int t = 0; t < 32; t++) m = fmaxf(m, s[t]);
#pragma unroll
    for (int off = 32; off >= 1; off >>= 1) m = fmaxf(m, __shfl_xor(m, off));

    // in-place convert scores -> orderable keys (bit pattern kept in float reg)
#pragma unroll
    for (int t = 0; t < 32; t++) s[t] = __uint_as_float(f2key(s[t]));

    // bisection for the 64th-largest key
    uint32_t lo = 0u, hi = 0xFFFFFFFFu;
    while (lo < hi) {
        uint32_t mid = (uint32_t)(((uint64_t)lo + (uint64_t)hi + 1ull) >> 1);
        int c = 0;
#pragma unroll
        for (int t = 0; t < 32; t++)
            c += (int)__popcll(__ballot(__float_as_uint(s[t]) >= mid));
        if (c >= TOPKN) { lo = mid; if (c == TOPKN) { hi = mid; } }
        else hi = mid - 1;
    }
    const uint32_t thr = lo;

    // softmax over kept entries
    uint32_t keep = 0;
    float sum = 0.f;
#pragma unroll
    for (int t = 0; t < 32; t++) {
        uint32_t kk = __float_as_uint(s[t]);
        bool kp = (kk >= thr);
        float e = kp ? __expf(key2f(kk) - m) : 0.f;
        s[t] = e;
        sum += e;
        keep |= kp ? (1u << t) : 0u;
    }
#pragma unroll
    for (int off = 32; off >= 1; off >>= 1) sum += __shfl_xor(sum, off);
    const float rs = 1.f / sum;

    // compacted emit
    int base = 0;
    const unsigned long long below = (1ull << lane) - 1ull;
#pragma unroll
    for (int t = 0; t < 32; t++) {
        bool kp = (keep >> t) & 1u;
        unsigned long long mask = __ballot(kp);
        if (kp) {
            int pos = base + (int)__popcll(mask & below);
            if (pos < CAP) {
                tki[(size_t)row * CAP + pos] = (t << 6) + lane;
                tkp[(size_t)row * CAP + pos] = s[t] * rs;
            }
        }
        base += (int)__popcll(mask);
    }
    if (lane == 0) tkc[row] = base < CAP ? base : CAP;
}

// direct global->LDS 16B copy (no VGPR round-trip). lds base must be
// wave-uniform; HW scatters lane i to base + i*16 (m104/m108).
__device__ __forceinline__ void gload_lds16(const void* g, void* l) {
    __builtin_amdgcn_global_load_lds(
        (const __attribute__((address_space(1))) unsigned int*)g,
        (__attribute__((address_space(3))) unsigned int*)l,
        16, 0, 0);
}

// ---------------------------------------------------------------------------
// Kernel 2: scores + top-k + softmax probs.
// Block = 4 waves; each wave owns 2 query rows.  K staged via
// global_load_lds (linear LDS dest, pre-swizzled per-lane GLOBAL source):
// chunk layout Ks[j][swz] with swz = c ^ (j&7).
// __launch_bounds__(256,2): cap VGPR ~128 so the 64 score regs stay resident
// (R2's (256,4) forced VGPR=64 -> full score spill -> 50 GB scratch traffic).
// ---------------------------------------------------------------------------
__global__ __launch_bounds__(256, 2) void scores_topk(
    const float* __restrict__ qg, const float* __restrict__ kg,
    int* __restrict__ tki, float* __restrict__ tkp, int* __restrict__ tkc)
{
    __shared__ float4 Ks[2048];    // 32 KB  (128 keys x 16 chunks, swizzled)
    __shared__ float  qs[8][64];   // 2 KB
    const int bh = blockIdx.y;
    const int wave = threadIdx.x >> 6, lane = threadIdx.x & 63;
    const size_t kbase = (size_t)bh * NSEQ * DHEAD;

    // stage the block's 8 q rows (waves 0-1; covered by first barrier)
    if (threadIdx.x < 128) {
        int r = threadIdx.x >> 4, c4 = threadIdx.x & 15;
        *reinterpret_cast<float4*>(&qs[r][c4 << 2]) =
            *reinterpret_cast<const float4*>(
                &qg[((size_t)bh * NSEQ + blockIdx.x * 8 + r) * DHEAD + (c4 << 2)]);
    }

    float sA[32], sB[32];
#pragma unroll
    for (int t = 0; t < 32; t++) { sA[t] = 0.f; sB[t] = 0.f; }

    // staging geometry: chunk = rep*256 + wave*64 + lane (linear LDS dest);
    // j = chunk>>4 = rep*16 + wave*4 + (lane>>4); swz = lane&15; c = swz^(j&7)
    const int jw  = wave * 4 + (lane >> 4);
    const int swz = lane & 15;

#pragma unroll
    for (int KT = 0; KT < 16; KT++) {
        __syncthreads();   // previous tile's reads complete
#pragma unroll
        for (int rep = 0; rep < 8; rep++) {
            int j = rep * 16 + jw;
            int c = swz ^ (j & 7);
            gload_lds16(&kg[kbase + (size_t)(KT * 128 + j) * DHEAD + (c << 2)],
                        (char*)Ks + (rep * 4096 + wave * 1024));
        }
        __syncthreads();   // staging drained (vmcnt 0) for all waves
#pragma unroll
        for (int c = 0; c < 16; c++) {
            // q reads are same-address broadcasts (no bank conflict)
            float4 qa = *reinterpret_cast<const float4*>(&qs[wave * 2 + 0][c << 2]);
            float4 qb = *reinterpret_cast<const float4*>(&qs[wave * 2 + 1][c << 2]);
#pragma unroll
            for (int half = 0; half < 2; half++) {
                int j = (half << 6) + lane;
                float4 kv = Ks[(j << 4) + (c ^ (j & 7))];
                sA[KT * 2 + half] += qa.x * kv.x + qa.y * kv.y + qa.z * kv.z + qa.w * kv.w;
                sB[KT * 2 + half] += qb.x * kv.x + qb.y * kv.y + qb.z * kv.z + qb.w * kv.w;
            }
        }
    }
#pragma unroll
    for (int t = 0; t < 32; t++) { sA[t] *= 0.125f; sB[t] *= 0.125f; }

    const int nA = blockIdx.x * 8 + wave * 2;
    const int rowA = bh * NSEQ + nA;
    topk_softmax_emit(sA, rowA,     lane, tki, tkp, tkc);
    topk_softmax_emit(sB, rowA + 1, lane, tki, tkp, tkc);
}

// ---------------------------------------------------------------------------
// Kernel 3: one propagation step.  v_out[n] = sum_j p[n,j] * v_in[idx[n,j]];
// res(+)= sigmoid(alphas_raw[iter,h]) * v_out, res in [B,N,H*DH] layout.
// ---------------------------------------------------------------------------
__global__ __launch_bounds__(256) void prop(
    const float* __restrict__ vin, float* __restrict__ vout,
    float* __restrict__ res, const float* __restrict__ araw,
    const int* __restrict__ tki, const float* __restrict__ tkp,
    const int* __restrict__ tkc, int iter)
{
    const int row = blockIdx.x * 4 + (threadIdx.x >> 6);
    const int lane = threadIdx.x & 63;
    const int bh = row >> 11;
    const int h = bh & 15;
    const int cnt = tkc[row];
    const int* idx = tki + (size_t)row * CAP;
    const float* pr = tkp + (size_t)row * CAP;
    const float* vb = vin + (size_t)bh * NSEQ * DHEAD;

    float a0 = 0.f, a1 = 0.f, a2 = 0.f, a3 = 0.f;
    int j = 0;
    for (; j + 4 <= cnt; j += 4) {
        int i0 = idx[j], i1 = idx[j + 1], i2 = idx[j + 2], i3 = idx[j + 3];
        float p0 = pr[j], p1 = pr[j + 1], p2 = pr[j + 2], p3 = pr[j + 3];
        a0 += p0 * vb[(size_t)i0 * DHEAD + lane];
        a1 += p1 * vb[(size_t)i1 * DHEAD + lane];
        a2 += p2 * vb[(size_t)i2 * DHEAD + lane];
        a3 += p3 * vb[(size_t)i3 * DHEAD + lane];
    }
    for (; j < cnt; j++) a0 += pr[j] * vb[(size_t)idx[j] * DHEAD + lane];
    float acc = (a0 + a1) + (a2 + a3);

    vout[(size_t)row * DHEAD + lane] = acc;

    float ar = araw[iter * HHEADS + h];
    float alpha = 1.f / (1.f + __expf(-ar));
    const int b = row >> 15, n = row & 2047;
    size_t ro = ((size_t)(b * NSEQ + n)) * 1024 + h * DHEAD + lane;
    if (iter == 1) res[ro] = alpha * acc;
    else           res[ro] += alpha * acc;
}

// ---------------------------------------------------------------------------
// Kernel 4: output GEMM.  res[4096,1024] @ Wout[1024,1024] + bout -> out
// ---------------------------------------------------------------------------
__global__ __launch_bounds__(256) void out_gemm(
    const float* __restrict__ A, const float* __restrict__ W,
    const float* __restrict__ bias, float* __restrict__ out)
{
    __shared__ float As[16][64];
    __shared__ float Bs[16][64];
    const int tid = threadIdx.x;
    const int rowBase = blockIdx.y * 64;
    const int colBase = blockIdx.x * 64;
    const int tx = tid & 15, ty = tid >> 4;
    const int aRow = tid >> 2, aCol = (tid & 3) << 2;
    const int bRow = tid >> 4, bCol = (tid & 15) << 2;

    float acc[4][4] = {};
    for (int k0 = 0; k0 < 1024; k0 += 16) {
        float4 av = *reinterpret_cast<const float4*>(&A[(size_t)(rowBase + aRow) * 1024 + k0 + aCol]);
        float4 bv = *reinterpret_cast<const float4*>(&W[(size_t)(k0 + bRow) * 1024 + colBase + bCol]);
        __syncthreads();
        As[aCol + 0][aRow] = av.x; As[aCol + 1][aRow] = av.y;
        As[aCol + 2][aRow] = av.z; As[aCol + 3][aRow] = av.w;
        *reinterpret_cast<float4*>(&Bs[bRow][bCol]) = bv;
        __syncthreads();
#pragma unroll
        for (int kk = 0; kk < 16; kk++) {
            float4 a4 = *reinterpret_cast<const float4*>(&As[kk][ty << 2]);
            float4 b4 = *reinterpret_cast<const float4*>(&Bs[kk][tx << 2]);
            float ar[4] = {a4.x, a4.y, a4.z, a4.w};
            float br[4] = {b4.x, b4.y, b4.z, b4.w};
#pragma unroll
            for (int i = 0; i < 4; i++)
#pragma unroll
                for (int j = 0; j < 4; j++) acc[i][j] += ar[i] * br[j];
        }
    }
    float4 bb = *reinterpret_cast<const float4*>(&bias[colBase + (tx << 2)]);
#pragma unroll
    for (int i = 0; i < 4; i++) {
        int r = rowBase + (ty << 2) + i;
        float4 st;
        st.x = acc[i][0] + bb.x; st.y = acc[i][1] + bb.y;
        st.z = acc[i][2] + bb.z; st.w = acc[i][3] + bb.w;
        *reinterpret_cast<float4*>(&out[(size_t)r * 1024 + colBase + (tx << 2)]) = st;
    }
}

// ---------------------------------------------------------------------------
extern "C" void kernel_launch(void* const* d_in, const int* in_sizes, int n_in,
                              void* d_out, int out_size, void* d_ws, size_t ws_size,
                              hipStream_t stream)
{
    const float* x    = (const float*)d_in[0];
    const float* Wqkv = (const float*)d_in[1];
    const float* bqkv = (const float*)d_in[2];
    const float* Wout = (const float*)d_in[3];
    const float* bout = (const float*)d_in[4];
    const float* araw = (const float*)d_in[5];
    float* out = (float*)d_out;

    const size_t SEG = (size_t)1 << 22;   // 4M floats = one [B,H,N,DH] tensor
    float* ws = (float*)d_ws;
    float* q   = ws;                // [0, 4M)
    float* k   = q + SEG;           // [4M, 8M)
    float* v   = k + SEG;           // [8M, 12M)
    float* vA  = v + SEG;           // [12M, 16M)
    int*   tki = (int*)(vA + SEG);                  // 65536*68 ints
    float* tkp = (float*)(tki + (size_t)NROWS * CAP);
    int*   tkc = (int*)(tkp + (size_t)NROWS * CAP);
    float* res = q;                 // q is dead after scores_topk; alias

    qkv_gemm<<<dim3(48, 64), 256, 0, stream>>>(x, Wqkv, bqkv, q, k, v);
    scores_topk<<<dim3(256, 32), 256, 0, stream>>>(q, k, tki, tkp, tkc);
    prop<<<dim3(NROWS / 4), 256, 0, stream>>>(v,  vA, res, araw, tki, tkp, tkc, 1);
    prop<<<dim3(NROWS / 4), 256, 0, stream>>>(vA, v,  res, araw, tki, tkp, tkc, 2);
    prop<<<dim3(NROWS / 4), 256, 0, stream>>>(v,  vA, res, araw, tki, tkp, tkc, 3);
    out_gemm<<<dim3(16, 64), 256, 0, stream>>>(res, Wout, bout, out);
}

// Round 4
// 2381.737 us; speedup vs baseline: 7.0825x; 7.0825x over previous
//
#include <hip/hip_runtime.h>
#include <cstdint>
#include <cstddef>

#define HHEADS 16
#define DHEAD  64
#define NSEQ   2048
#define NBATCH 2
#define NDIM   1024
#define TOPKN  64
#define CAP    68
#define NROWS  (NBATCH*HHEADS*NSEQ)   // 65536

// ---------------------------------------------------------------------------
// Kernel 1: QKV GEMM.  x[4096,1024] @ Wqkv[1024,3072] + bqkv
// -> q,k,v each laid out [B,H,N,DH]
// ---------------------------------------------------------------------------
__global__ __launch_bounds__(256) void qkv_gemm(
    const float* __restrict__ x, const float* __restrict__ W,
    const float* __restrict__ bias,
    float* __restrict__ qout, float* __restrict__ kout, float* __restrict__ vout)
{
    __shared__ float As[16][64];   // transposed A tile
    __shared__ float Bs[16][64];
    const int tid = threadIdx.x;
    const int rowBase = blockIdx.y * 64;
    const int colBase = blockIdx.x * 64;
    const int tx = tid & 15, ty = tid >> 4;
    const int aRow = tid >> 2, aCol = (tid & 3) << 2;
    const int bRow = tid >> 4, bCol = (tid & 15) << 2;

    float acc[4][4] = {};
    for (int k0 = 0; k0 < NDIM; k0 += 16) {
        float4 av = *reinterpret_cast<const float4*>(&x[(size_t)(rowBase + aRow) * NDIM + k0 + aCol]);
        float4 bv = *reinterpret_cast<const float4*>(&W[(size_t)(k0 + bRow) * 3072 + colBase + bCol]);
        __syncthreads();
        As[aCol + 0][aRow] = av.x; As[aCol + 1][aRow] = av.y;
        As[aCol + 2][aRow] = av.z; As[aCol + 3][aRow] = av.w;
        *reinterpret_cast<float4*>(&Bs[bRow][bCol]) = bv;
        __syncthreads();
#pragma unroll
        for (int kk = 0; kk < 16; kk++) {
            float4 a4 = *reinterpret_cast<const float4*>(&As[kk][ty << 2]);
            float4 b4 = *reinterpret_cast<const float4*>(&Bs[kk][tx << 2]);
            float ar[4] = {a4.x, a4.y, a4.z, a4.w};
            float br[4] = {b4.x, b4.y, b4.z, b4.w};
#pragma unroll
            for (int i = 0; i < 4; i++)
#pragma unroll
                for (int j = 0; j < 4; j++) acc[i][j] += ar[i] * br[j];
        }
    }
    const int which = colBase >> 10;
    const int h = (colBase & 1023) >> 6;
    float* dst = which == 0 ? qout : (which == 1 ? kout : vout);
    const int d0 = (colBase + (tx << 2)) & 63;
    float4 bb = *reinterpret_cast<const float4*>(&bias[colBase + (tx << 2)]);
#pragma unroll
    for (int i = 0; i < 4; i++) {
        int r = rowBase + (ty << 2) + i;
        int b = r >> 11, n = r & 2047;
        size_t o = ((size_t)((b << 4) + h) * NSEQ + n) * DHEAD + d0;
        float4 st;
        st.x = acc[i][0] + bb.x; st.y = acc[i][1] + bb.y;
        st.z = acc[i][2] + bb.z; st.w = acc[i][3] + bb.w;
        *reinterpret_cast<float4*>(&dst[o]) = st;
    }
}

// ---------------------------------------------------------------------------
// order-preserving float<->uint key transforms
// ---------------------------------------------------------------------------
__device__ __forceinline__ uint32_t f2key(float f) {
    uint32_t u = __float_as_uint(f);
    return (u & 0x80000000u) ? ~u : (u | 0x80000000u);
}
__device__ __forceinline__ float key2f(uint32_t k) {
    uint32_t u = (k & 0x80000000u) ? (k & 0x7FFFFFFFu) : ~k;
    return __uint_as_float(u);
}

// Per-row top-64 + softmax + compacted emit, entirely from 32 key registers.
// k[t] holds key of score j = (t>>2)*256 + lane*4 + (t&3).
__device__ __forceinline__ void topk_emit(
    uint32_t (&k)[32], float m, int row, int lane,
    int* __restrict__ tki, float* __restrict__ tkp, int* __restrict__ tkc)
{
    // bisection for the 64th-largest key (ballot count, wave-uniform scalar)
    uint32_t lo = 0u, hi = 0xFFFFFFFFu;
    while (lo < hi) {
        uint32_t mid = (uint32_t)(((uint64_t)lo + (uint64_t)hi + 1ull) >> 1);
        int c = 0;
#pragma unroll
        for (int t = 0; t < 32; t++)
            c += (int)__popcll(__ballot(k[t] >= mid));
        if (c >= TOPKN) { lo = mid; if (c == TOPKN) { hi = mid; } }
        else hi = mid - 1;
    }
    const uint32_t thr = lo;

    // softmax over kept entries (overwrite k[t] with exp bits; keep mask)
    uint32_t keep = 0;
    float sum = 0.f;
#pragma unroll
    for (int t = 0; t < 32; t++) {
        bool kp = (k[t] >= thr);
        float e = kp ? __expf(key2f(k[t]) - m) : 0.f;
        k[t] = __float_as_uint(e);
        sum += e;
        keep |= kp ? (1u << t) : 0u;
    }
#pragma unroll
    for (int off = 32; off >= 1; off >>= 1) sum += __shfl_xor(sum, off);
    const float rs = 1.f / sum;

    // compacted emit
    int base = 0;
    const unsigned long long below = (1ull << lane) - 1ull;
#pragma unroll
    for (int t = 0; t < 32; t++) {
        bool kp = (keep >> t) & 1u;
        unsigned long long mask = __ballot(kp);
        if (kp) {
            int pos = base + (int)__popcll(mask & below);
            if (pos < CAP) {
                tki[(size_t)row * CAP + pos] = ((t >> 2) << 8) + (lane << 2) + (t & 3);
                tkp[(size_t)row * CAP + pos] = __uint_as_float(k[t]) * rs;
            }
        }
        base += (int)__popcll(mask);
    }
    if (lane == 0) tkc[row] = base < CAP ? base : CAP;
}

// direct global->LDS 16B copy (no VGPR round-trip). lds base must be
// wave-uniform; HW scatters lane i to base + i*16 (m104/m108).
__device__ __forceinline__ void gload_lds16(const void* g, void* l) {
    __builtin_amdgcn_global_load_lds(
        (const __attribute__((address_space(1))) unsigned int*)g,
        (__attribute__((address_space(3))) unsigned int*)l,
        16, 0, 0);
}

// ---------------------------------------------------------------------------
// Kernel 2: scores + top-k + softmax probs.
// Block = 4 waves; each wave owns 2 query rows.  Per 128-key tile the full
// 64-dim dot products FINALIZE (tile holds all dims), so accumulators live
// only 4 regs; finished keys bounce through LDS keyk[8][2048].  Top-k then
// pulls one row back into 32 registers (8x b128 conflict-free stripes) and
// runs bisection/softmax/emit with zero LDS re-reads.  K tile double-buffered
// via global_load_lds issued before compute (drain covered by compute).
// ---------------------------------------------------------------------------
__global__ __launch_bounds__(256) void scores_topk(
    const float* __restrict__ qg, const float* __restrict__ kg,
    int* __restrict__ tki, float* __restrict__ tkp, int* __restrict__ tkc)
{
    __shared__ float4   Ks[2][2048];     // 64 KB (2 x 128 keys x 16 chunks, swizzled)
    __shared__ float    qs[8][64];       // 2 KB
    __shared__ uint32_t keyk[8][2048];   // 64 KB score-key bounce
    const int bh = blockIdx.y;
    const int wave = threadIdx.x >> 6, lane = threadIdx.x & 63;
    const size_t kbase = (size_t)bh * NSEQ * DHEAD;

    // stage the block's 8 q rows
    if (threadIdx.x < 128) {
        int r = threadIdx.x >> 4, c4 = threadIdx.x & 15;
        *reinterpret_cast<float4*>(&qs[r][c4 << 2]) =
            *reinterpret_cast<const float4*>(
                &qg[((size_t)bh * NSEQ + blockIdx.x * 8 + r) * DHEAD + (c4 << 2)]);
    }

    // staging geometry: chunk = rep*256 + wave*64 + lane (linear LDS dest);
    // j = chunk>>4 = rep*16 + wave*4 + (lane>>4); swz = lane&15; c = swz^(j&7)
    const int jw  = wave * 4 + (lane >> 4);
    const int swz = lane & 15;
    auto stage = [&](int T, int buf) {
#pragma unroll
        for (int rep = 0; rep < 8; rep++) {
            int j = rep * 16 + jw;
            int c = swz ^ (j & 7);
            gload_lds16(&kg[kbase + (size_t)(T * 128 + j) * DHEAD + (c << 2)],
                        (char*)&Ks[buf][0] + (rep * 4096 + wave * 1024));
        }
    };

    stage(0, 0);
    __syncthreads();   // tile 0 staged (and qs visible)

    const int rA = wave * 2, rB = rA + 1;
    float mA = -3.4e38f, mB = -3.4e38f;

    for (int KT = 0; KT < 16; KT++) {
        const int cur = KT & 1;
        if (KT < 15) stage(KT + 1, cur ^ 1);   // issue-early; drained at barrier

        float sA0 = 0.f, sA1 = 0.f, sB0 = 0.f, sB1 = 0.f;
#pragma unroll
        for (int c = 0; c < 16; c++) {
            // q reads are same-address broadcasts (no bank conflict)
            float4 qa = *reinterpret_cast<const float4*>(&qs[rA][c << 2]);
            float4 qb = *reinterpret_cast<const float4*>(&qs[rB][c << 2]);
            int j0 = lane, j1 = 64 + lane;
            float4 kv0 = Ks[cur][(j0 << 4) + (c ^ (j0 & 7))];
            float4 kv1 = Ks[cur][(j1 << 4) + (c ^ (j1 & 7))];
            sA0 += qa.x * kv0.x + qa.y * kv0.y + qa.z * kv0.z + qa.w * kv0.w;
            sA1 += qa.x * kv1.x + qa.y * kv1.y + qa.z * kv1.z + qa.w * kv1.w;
            sB0 += qb.x * kv0.x + qb.y * kv0.y + qb.z * kv0.z + qb.w * kv0.w;
            sB1 += qb.x * kv1.x + qb.y * kv1.y + qb.z * kv1.z + qb.w * kv1.w;
        }
        // finalize this tile's 4 scores: scale, track row max, key-encode, park in LDS
        sA0 *= 0.125f; sA1 *= 0.125f; sB0 *= 0.125f; sB1 *= 0.125f;
        mA = fmaxf(mA, fmaxf(sA0, sA1));
        mB = fmaxf(mB, fmaxf(sB0, sB1));
        keyk[rA][KT * 128 + lane]      = f2key(sA0);
        keyk[rA][KT * 128 + 64 + lane] = f2key(sA1);
        keyk[rB][KT * 128 + lane]      = f2key(sB0);
        keyk[rB][KT * 128 + 64 + lane] = f2key(sB1);
        __syncthreads();   // drains staging vmcnt; all waves done with Ks[cur]
    }

    // wave-wide row maxima (exact, order-independent)
#pragma unroll
    for (int off = 32; off >= 1; off >>= 1) {
        mA = fmaxf(mA, __shfl_xor(mA, off));
        mB = fmaxf(mB, __shfl_xor(mB, off));
    }

    const int rowA = bh * NSEQ + blockIdx.x * 8 + wave * 2;

    // row A: pull 32 keys into regs (8x b128, consecutive-lane stripes)
    {
        const uint4* src = reinterpret_cast<const uint4*>(&keyk[rA][0]);
        uint32_t k[32];
#pragma unroll
        for (int p = 0; p < 8; p++) {
            uint4 c4 = src[p * 64 + lane];
            k[p * 4 + 0] = c4.x; k[p * 4 + 1] = c4.y;
            k[p * 4 + 2] = c4.z; k[p * 4 + 3] = c4.w;
        }
        topk_emit(k, mA, rowA, lane, tki, tkp, tkc);
    }
    // row B
    {
        const uint4* src = reinterpret_cast<const uint4*>(&keyk[rB][0]);
        uint32_t k[32];
#pragma unroll
        for (int p = 0; p < 8; p++) {
            uint4 c4 = src[p * 64 + lane];
            k[p * 4 + 0] = c4.x; k[p * 4 + 1] = c4.y;
            k[p * 4 + 2] = c4.z; k[p * 4 + 3] = c4.w;
        }
        topk_emit(k, mB, rowA + 1, lane, tki, tkp, tkc);
    }
}

// ---------------------------------------------------------------------------
// Kernel 3: one propagation step.  v_out[n] = sum_j p[n,j] * v_in[idx[n,j]];
// res(+)= sigmoid(alphas_raw[iter,h]) * v_out, res in [B,N,H*DH] layout.
// ---------------------------------------------------------------------------
__global__ __launch_bounds__(256) void prop(
    const float* __restrict__ vin, float* __restrict__ vout,
    float* __restrict__ res, const float* __restrict__ araw,
    const int* __restrict__ tki, const float* __restrict__ tkp,
    const int* __restrict__ tkc, int iter)
{
    const int row = blockIdx.x * 4 + (threadIdx.x >> 6);
    const int lane = threadIdx.x & 63;
    const int bh = row >> 11;
    const int h = bh & 15;
    const int cnt = tkc[row];
    const int* idx = tki + (size_t)row * CAP;
    const float* pr = tkp + (size_t)row * CAP;
    const float* vb = vin + (size_t)bh * NSEQ * DHEAD;

    float a0 = 0.f, a1 = 0.f, a2 = 0.f, a3 = 0.f;
    int j = 0;
    for (; j + 4 <= cnt; j += 4) {
        int i0 = idx[j], i1 = idx[j + 1], i2 = idx[j + 2], i3 = idx[j + 3];
        float p0 = pr[j], p1 = pr[j + 1], p2 = pr[j + 2], p3 = pr[j + 3];
        a0 += p0 * vb[(size_t)i0 * DHEAD + lane];
        a1 += p1 * vb[(size_t)i1 * DHEAD + lane];
        a2 += p2 * vb[(size_t)i2 * DHEAD + lane];
        a3 += p3 * vb[(size_t)i3 * DHEAD + lane];
    }
    for (; j < cnt; j++) a0 += pr[j] * vb[(size_t)idx[j] * DHEAD + lane];
    float acc = (a0 + a1) + (a2 + a3);

    vout[(size_t)row * DHEAD + lane] = acc;

    float ar = araw[iter * HHEADS + h];
    float alpha = 1.f / (1.f + __expf(-ar));
    const int b = row >> 15, n = row & 2047;
    size_t ro = ((size_t)(b * NSEQ + n)) * 1024 + h * DHEAD + lane;
    if (iter == 1) res[ro] = alpha * acc;
    else           res[ro] += alpha * acc;
}

// ---------------------------------------------------------------------------
// Kernel 4: output GEMM.  res[4096,1024] @ Wout[1024,1024] + bout -> out
// ---------------------------------------------------------------------------
__global__ __launch_bounds__(256) void out_gemm(
    const float* __restrict__ A, const float* __restrict__ W,
    const float* __restrict__ bias, float* __restrict__ out)
{
    __shared__ float As[16][64];
    __shared__ float Bs[16][64];
    const int tid = threadIdx.x;
    const int rowBase = blockIdx.y * 64;
    const int colBase = blockIdx.x * 64;
    const int tx = tid & 15, ty = tid >> 4;
    const int aRow = tid >> 2, aCol = (tid & 3) << 2;
    const int bRow = tid >> 4, bCol = (tid & 15) << 2;

    float acc[4][4] = {};
    for (int k0 = 0; k0 < 1024; k0 += 16) {
        float4 av = *reinterpret_cast<const float4*>(&A[(size_t)(rowBase + aRow) * 1024 + k0 + aCol]);
        float4 bv = *reinterpret_cast<const float4*>(&W[(size_t)(k0 + bRow) * 1024 + colBase + bCol]);
        __syncthreads();
        As[aCol + 0][aRow] = av.x; As[aCol + 1][aRow] = av.y;
        As[aCol + 2][aRow] = av.z; As[aCol + 3][aRow] = av.w;
        *reinterpret_cast<float4*>(&Bs[bRow][bCol]) = bv;
        __syncthreads();
#pragma unroll
        for (int kk = 0; kk < 16; kk++) {
            float4 a4 = *reinterpret_cast<const float4*>(&As[kk][ty << 2]);
            float4 b4 = *reinterpret_cast<const float4*>(&Bs[kk][tx << 2]);
            float ar[4] = {a4.x, a4.y, a4.z, a4.w};
            float br[4] = {b4.x, b4.y, b4.z, b4.w};
#pragma unroll
            for (int i = 0; i < 4; i++)
#pragma unroll
                for (int j = 0; j < 4; j++) acc[i][j] += ar[i] * br[j];
        }
    }
    float4 bb = *reinterpret_cast<const float4*>(&bias[colBase + (tx << 2)]);
#pragma unroll
    for (int i = 0; i < 4; i++) {
        int r = rowBase + (ty << 2) + i;
        float4 st;
        st.x = acc[i][0] + bb.x; st.y = acc[i][1] + bb.y;
        st.z = acc[i][2] + bb.z; st.w = acc[i][3] + bb.w;
        *reinterpret_cast<float4*>(&out[(size_t)r * 1024 + colBase + (tx << 2)]) = st;
    }
}

// ---------------------------------------------------------------------------
extern "C" void kernel_launch(void* const* d_in, const int* in_sizes, int n_in,
                              void* d_out, int out_size, void* d_ws, size_t ws_size,
                              hipStream_t stream)
{
    const float* x    = (const float*)d_in[0];
    const float* Wqkv = (const float*)d_in[1];
    const float* bqkv = (const float*)d_in[2];
    const float* Wout = (const float*)d_in[3];
    const float* bout = (const float*)d_in[4];
    const float* araw = (const float*)d_in[5];
    float* out = (float*)d_out;

    const size_t SEG = (size_t)1 << 22;   // 4M floats = one [B,H,N,DH] tensor
    float* ws = (float*)d_ws;
    float* q   = ws;                // [0, 4M)
    float* k   = q + SEG;           // [4M, 8M)
    float* v   = k + SEG;           // [8M, 12M)
    float* vA  = v + SEG;           // [12M, 16M)
    int*   tki = (int*)(vA + SEG);                  // 65536*68 ints
    float* tkp = (float*)(tki + (size_t)NROWS * CAP);
    int*   tkc = (int*)(tkp + (size_t)NROWS * CAP);
    float* res = q;                 // q is dead after scores_topk; alias

    qkv_gemm<<<dim3(48, 64), 256, 0, stream>>>(x, Wqkv, bqkv, q, k, v);
    scores_topk<<<dim3(256, 32), 256, 0, stream>>>(q, k, tki, tkp, tkc);
    prop<<<dim3(NROWS / 4), 256, 0, stream>>>(v,  vA, res, araw, tki, tkp, tkc, 1);
    prop<<<dim3(NROWS / 4), 256, 0, stream>>>(vA, v,  res, araw, tki, tkp, tkc, 2);
    prop<<<dim3(NROWS / 4), 256, 0, stream>>>(v,  vA, res, araw, tki, tkp, tkc, 3);
    out_gemm<<<dim3(16, 64), 256, 0, stream>>>(res, Wout, bout, out);
}

// Round 5
// 2377.400 us; speedup vs baseline: 7.0954x; 1.0018x over previous
//
#include <hip/hip_runtime.h>
#include <cstdint>
#include <cstddef>

#define HHEADS 16
#define DHEAD  64
#define NSEQ   2048
#define NBATCH 2
#define NDIM   1024
#define TOPKN  64
#define CAP    68
#define NROWS  (NBATCH*HHEADS*NSEQ)   // 65536

// ---------------------------------------------------------------------------
// Kernel 1: QKV GEMM.  x[4096,1024] @ Wqkv[1024,3072] + bqkv
// -> q,k,v each laid out [B,H,N,DH]
// ---------------------------------------------------------------------------
__global__ __launch_bounds__(256) void qkv_gemm(
    const float* __restrict__ x, const float* __restrict__ W,
    const float* __restrict__ bias,
    float* __restrict__ qout, float* __restrict__ kout, float* __restrict__ vout)
{
    __shared__ float As[16][64];   // transposed A tile
    __shared__ float Bs[16][64];
    const int tid = threadIdx.x;
    const int rowBase = blockIdx.y * 64;
    const int colBase = blockIdx.x * 64;
    const int tx = tid & 15, ty = tid >> 4;
    const int aRow = tid >> 2, aCol = (tid & 3) << 2;
    const int bRow = tid >> 4, bCol = (tid & 15) << 2;

    float acc[4][4] = {};
    for (int k0 = 0; k0 < NDIM; k0 += 16) {
        float4 av = *reinterpret_cast<const float4*>(&x[(size_t)(rowBase + aRow) * NDIM + k0 + aCol]);
        float4 bv = *reinterpret_cast<const float4*>(&W[(size_t)(k0 + bRow) * 3072 + colBase + bCol]);
        __syncthreads();
        As[aCol + 0][aRow] = av.x; As[aCol + 1][aRow] = av.y;
        As[aCol + 2][aRow] = av.z; As[aCol + 3][aRow] = av.w;
        *reinterpret_cast<float4*>(&Bs[bRow][bCol]) = bv;
        __syncthreads();
#pragma unroll
        for (int kk = 0; kk < 16; kk++) {
            float4 a4 = *reinterpret_cast<const float4*>(&As[kk][ty << 2]);
            float4 b4 = *reinterpret_cast<const float4*>(&Bs[kk][tx << 2]);
            float ar[4] = {a4.x, a4.y, a4.z, a4.w};
            float br[4] = {b4.x, b4.y, b4.z, b4.w};
#pragma unroll
            for (int i = 0; i < 4; i++)
#pragma unroll
                for (int j = 0; j < 4; j++) acc[i][j] += ar[i] * br[j];
        }
    }
    const int which = colBase >> 10;
    const int h = (colBase & 1023) >> 6;
    float* dst = which == 0 ? qout : (which == 1 ? kout : vout);
    const int d0 = (colBase + (tx << 2)) & 63;
    float4 bb = *reinterpret_cast<const float4*>(&bias[colBase + (tx << 2)]);
#pragma unroll
    for (int i = 0; i < 4; i++) {
        int r = rowBase + (ty << 2) + i;
        int b = r >> 11, n = r & 2047;
        size_t o = ((size_t)((b << 4) + h) * NSEQ + n) * DHEAD + d0;
        float4 st;
        st.x = acc[i][0] + bb.x; st.y = acc[i][1] + bb.y;
        st.z = acc[i][2] + bb.z; st.w = acc[i][3] + bb.w;
        *reinterpret_cast<float4*>(&dst[o]) = st;
    }
}

// ---------------------------------------------------------------------------
// order-preserving float<->uint key transforms
// ---------------------------------------------------------------------------
__device__ __forceinline__ uint32_t f2key(float f) {
    uint32_t u = __float_as_uint(f);
    return (u & 0x80000000u) ? ~u : (u | 0x80000000u);
}
__device__ __forceinline__ float key2f(uint32_t k) {
    uint32_t u = (k & 0x80000000u) ? (k & 0x7FFFFFFFu) : ~k;
    return __uint_as_float(u);
}

// Per-row top-64 + softmax + compacted emit, entirely from 32 key registers.
// k[t] holds key of score j = (t>>2)*256 + lane*4 + (t&3).
__device__ __forceinline__ void topk_emit(
    uint32_t (&k)[32], float m, int row, int lane,
    int* __restrict__ tki, float* __restrict__ tkp, int* __restrict__ tkc)
{
    // bisection for the 64th-largest key (ballot count, wave-uniform scalar)
    uint32_t lo = 0u, hi = 0xFFFFFFFFu;
    while (lo < hi) {
        uint32_t mid = (uint32_t)(((uint64_t)lo + (uint64_t)hi + 1ull) >> 1);
        int c = 0;
#pragma unroll
        for (int t = 0; t < 32; t++)
            c += (int)__popcll(__ballot(k[t] >= mid));
        if (c >= TOPKN) { lo = mid; if (c == TOPKN) { hi = mid; } }
        else hi = mid - 1;
    }
    const uint32_t thr = lo;

    // softmax over kept entries (overwrite k[t] with exp bits; keep mask)
    uint32_t keep = 0;
    float sum = 0.f;
#pragma unroll
    for (int t = 0; t < 32; t++) {
        bool kp = (k[t] >= thr);
        float e = kp ? __expf(key2f(k[t]) - m) : 0.f;
        k[t] = __float_as_uint(e);
        sum += e;
        keep |= kp ? (1u << t) : 0u;
    }
#pragma unroll
    for (int off = 32; off >= 1; off >>= 1) sum += __shfl_xor(sum, off);
    const float rs = 1.f / sum;

    // compacted emit
    int base = 0;
    const unsigned long long below = (1ull << lane) - 1ull;
#pragma unroll
    for (int t = 0; t < 32; t++) {
        bool kp = (keep >> t) & 1u;
        unsigned long long mask = __ballot(kp);
        if (kp) {
            int pos = base + (int)__popcll(mask & below);
            if (pos < CAP) {
                tki[(size_t)row * CAP + pos] = ((t >> 2) << 8) + (lane << 2) + (t & 3);
                tkp[(size_t)row * CAP + pos] = __uint_as_float(k[t]) * rs;
            }
        }
        base += (int)__popcll(mask);
    }
    if (lane == 0) tkc[row] = base < CAP ? base : CAP;
}

// direct global->LDS 16B copy (no VGPR round-trip). lds base must be
// wave-uniform; HW scatters lane i to base + i*16 (m104/m108).
__device__ __forceinline__ void gload_lds16(const void* g, void* l) {
    __builtin_amdgcn_global_load_lds(
        (const __attribute__((address_space(1))) unsigned int*)g,
        (__attribute__((address_space(3))) unsigned int*)l,
        16, 0, 0);
}

// ---------------------------------------------------------------------------
// Kernel 2a (split path): scores only.  Block = 4 waves, 4 rows/wave (16
// rows/block) -> K LDS-read traffic halved vs 2 rows/wave.  Keys stream to
// global keyg[row][2048] (coalesced u32 stores).  LDS = 68 KB -> 2 blocks/CU.
// ---------------------------------------------------------------------------
__global__ __launch_bounds__(256) void scores_kernel(
    const float* __restrict__ qg, const float* __restrict__ kg,
    uint32_t* __restrict__ keyg)
{
    __shared__ float4 Ks[2][2048];   // 64 KB (2 x 128 keys x 16 chunks, swizzled)
    __shared__ float  qs[16][64];    // 4 KB
    const int bh = blockIdx.y;
    const int wave = threadIdx.x >> 6, lane = threadIdx.x & 63;
    const size_t kbase = (size_t)bh * NSEQ * DHEAD;

    // stage the block's 16 q rows (all 256 threads, one float4 each)
    {
        int r = threadIdx.x >> 4, c4 = threadIdx.x & 15;
        *reinterpret_cast<float4*>(&qs[r][c4 << 2]) =
            *reinterpret_cast<const float4*>(
                &qg[((size_t)bh * NSEQ + blockIdx.x * 16 + r) * DHEAD + (c4 << 2)]);
    }

    // staging geometry: chunk = rep*256 + wave*64 + lane (linear LDS dest);
    // j = chunk>>4 = rep*16 + wave*4 + (lane>>4); swz = lane&15; c = swz^(j&7)
    const int jw  = wave * 4 + (lane >> 4);
    const int swz = lane & 15;
    auto stage = [&](int T, int buf) {
#pragma unroll
        for (int rep = 0; rep < 8; rep++) {
            int j = rep * 16 + jw;
            int c = swz ^ (j & 7);
            gload_lds16(&kg[kbase + (size_t)(T * 128 + j) * DHEAD + (c << 2)],
                        (char*)&Ks[buf][0] + (rep * 4096 + wave * 1024));
        }
    };

    stage(0, 0);
    __syncthreads();   // tile 0 staged (and qs visible)

    const int rA = wave * 4;
    const size_t rowBase = (size_t)bh * NSEQ + blockIdx.x * 16 + rA;

    for (int KT = 0; KT < 16; KT++) {
        const int cur = KT & 1;
        if (KT < 15) stage(KT + 1, cur ^ 1);   // issue-early; drained at barrier

        float acc[4][2];
#pragma unroll
        for (int r = 0; r < 4; r++) { acc[r][0] = 0.f; acc[r][1] = 0.f; }

#pragma unroll
        for (int c = 0; c < 16; c++) {
            int j0 = lane, j1 = 64 + lane;
            float4 kv0 = Ks[cur][(j0 << 4) + (c ^ (j0 & 7))];
            float4 kv1 = Ks[cur][(j1 << 4) + (c ^ (j1 & 7))];
#pragma unroll
            for (int r = 0; r < 4; r++) {
                // q reads are same-address broadcasts (no bank conflict)
                float4 qr = *reinterpret_cast<const float4*>(&qs[rA + r][c << 2]);
                acc[r][0] += qr.x * kv0.x + qr.y * kv0.y + qr.z * kv0.z + qr.w * kv0.w;
                acc[r][1] += qr.x * kv1.x + qr.y * kv1.y + qr.z * kv1.z + qr.w * kv1.w;
            }
        }
        // finalize this tile's 8 scores: scale, key-encode, stream to global
#pragma unroll
        for (int r = 0; r < 4; r++) {
            size_t ro = (rowBase + r) * 2048 + KT * 128;
            keyg[ro + lane]      = f2key(acc[r][0] * 0.125f);
            keyg[ro + 64 + lane] = f2key(acc[r][1] * 0.125f);
        }
        __syncthreads();   // drains staging vmcnt; all waves done with Ks[cur]
    }
}

// ---------------------------------------------------------------------------
// Kernel 2b (split path): top-k + softmax from keyg.  1 wave per row, no LDS
// -> high occupancy hides the bisection's serial chain and the key reload.
// Row max recovered exactly from keys (order-preserving transform).
// ---------------------------------------------------------------------------
__global__ __launch_bounds__(256) void topk_kernel(
    const uint32_t* __restrict__ keyg,
    int* __restrict__ tki, float* __restrict__ tkp, int* __restrict__ tkc)
{
    const int row = blockIdx.x * 4 + (threadIdx.x >> 6);
    const int lane = threadIdx.x & 63;
    const uint4* src = reinterpret_cast<const uint4*>(keyg + (size_t)row * 2048);

    uint32_t k[32];
#pragma unroll
    for (int p = 0; p < 8; p++) {
        uint4 c4 = src[p * 64 + lane];
        k[p * 4 + 0] = c4.x; k[p * 4 + 1] = c4.y;
        k[p * 4 + 2] = c4.z; k[p * 4 + 3] = c4.w;
    }
    uint32_t km = 0;
#pragma unroll
    for (int t = 0; t < 32; t++) km = k[t] > km ? k[t] : km;
#pragma unroll
    for (int off = 32; off >= 1; off >>= 1) {
        uint32_t o = __shfl_xor(km, off);
        km = o > km ? o : km;
    }
    topk_emit(k, key2f(km), row, lane, tki, tkp, tkc);
}

// ---------------------------------------------------------------------------
// Kernel 2 (fallback, fused): scores + top-k via LDS key bounce (R4 design).
// Used when ws_size can't hold the 512 MB keyg scratch.
// ---------------------------------------------------------------------------
__global__ __launch_bounds__(256) void scores_topk(
    const float* __restrict__ qg, const float* __restrict__ kg,
    int* __restrict__ tki, float* __restrict__ tkp, int* __restrict__ tkc)
{
    __shared__ float4   Ks[2][2048];     // 64 KB
    __shared__ float    qs[8][64];       // 2 KB
    __shared__ uint32_t keyk[8][2048];   // 64 KB score-key bounce
    const int bh = blockIdx.y;
    const int wave = threadIdx.x >> 6, lane = threadIdx.x & 63;
    const size_t kbase = (size_t)bh * NSEQ * DHEAD;

    if (threadIdx.x < 128) {
        int r = threadIdx.x >> 4, c4 = threadIdx.x & 15;
        *reinterpret_cast<float4*>(&qs[r][c4 << 2]) =
            *reinterpret_cast<const float4*>(
                &qg[((size_t)bh * NSEQ + blockIdx.x * 8 + r) * DHEAD + (c4 << 2)]);
    }

    const int jw  = wave * 4 + (lane >> 4);
    const int swz = lane & 15;
    auto stage = [&](int T, int buf) {
#pragma unroll
        for (int rep = 0; rep < 8; rep++) {
            int j = rep * 16 + jw;
            int c = swz ^ (j & 7);
            gload_lds16(&kg[kbase + (size_t)(T * 128 + j) * DHEAD + (c << 2)],
                        (char*)&Ks[buf][0] + (rep * 4096 + wave * 1024));
        }
    };

    stage(0, 0);
    __syncthreads();

    const int rA = wave * 2, rB = rA + 1;
    float mA = -3.4e38f, mB = -3.4e38f;

    for (int KT = 0; KT < 16; KT++) {
        const int cur = KT & 1;
        if (KT < 15) stage(KT + 1, cur ^ 1);

        float sA0 = 0.f, sA1 = 0.f, sB0 = 0.f, sB1 = 0.f;
#pragma unroll
        for (int c = 0; c < 16; c++) {
            float4 qa = *reinterpret_cast<const float4*>(&qs[rA][c << 2]);
            float4 qb = *reinterpret_cast<const float4*>(&qs[rB][c << 2]);
            int j0 = lane, j1 = 64 + lane;
            float4 kv0 = Ks[cur][(j0 << 4) + (c ^ (j0 & 7))];
            float4 kv1 = Ks[cur][(j1 << 4) + (c ^ (j1 & 7))];
            sA0 += qa.x * kv0.x + qa.y * kv0.y + qa.z * kv0.z + qa.w * kv0.w;
            sA1 += qa.x * kv1.x + qa.y * kv1.y + qa.z * kv1.z + qa.w * kv1.w;
            sB0 += qb.x * kv0.x + qb.y * kv0.y + qb.z * kv0.z + qb.w * kv0.w;
            sB1 += qb.x * kv1.x + qb.y * kv1.y + qb.z * kv1.z + qb.w * kv1.w;
        }
        sA0 *= 0.125f; sA1 *= 0.125f; sB0 *= 0.125f; sB1 *= 0.125f;
        mA = fmaxf(mA, fmaxf(sA0, sA1));
        mB = fmaxf(mB, fmaxf(sB0, sB1));
        keyk[rA][KT * 128 + lane]      = f2key(sA0);
        keyk[rA][KT * 128 + 64 + lane] = f2key(sA1);
        keyk[rB][KT * 128 + lane]      = f2key(sB0);
        keyk[rB][KT * 128 + 64 + lane] = f2key(sB1);
        __syncthreads();
    }

#pragma unroll
    for (int off = 32; off >= 1; off >>= 1) {
        mA = fmaxf(mA, __shfl_xor(mA, off));
        mB = fmaxf(mB, __shfl_xor(mB, off));
    }

    const int rowA = bh * NSEQ + blockIdx.x * 8 + wave * 2;
    {
        const uint4* src = reinterpret_cast<const uint4*>(&keyk[rA][0]);
        uint32_t k[32];
#pragma unroll
        for (int p = 0; p < 8; p++) {
            uint4 c4 = src[p * 64 + lane];
            k[p * 4 + 0] = c4.x; k[p * 4 + 1] = c4.y;
            k[p * 4 + 2] = c4.z; k[p * 4 + 3] = c4.w;
        }
        topk_emit(k, mA, rowA, lane, tki, tkp, tkc);
    }
    {
        const uint4* src = reinterpret_cast<const uint4*>(&keyk[rB][0]);
        uint32_t k[32];
#pragma unroll
        for (int p = 0; p < 8; p++) {
            uint4 c4 = src[p * 64 + lane];
            k[p * 4 + 0] = c4.x; k[p * 4 + 1] = c4.y;
            k[p * 4 + 2] = c4.z; k[p * 4 + 3] = c4.w;
        }
        topk_emit(k, mB, rowA + 1, lane, tki, tkp, tkc);
    }
}

// ---------------------------------------------------------------------------
// Kernel 3: one propagation step.  v_out[n] = sum_j p[n,j] * v_in[idx[n,j]];
// res(+)= sigmoid(alphas_raw[iter,h]) * v_out, res in [B,N,H*DH] layout.
// ---------------------------------------------------------------------------
__global__ __launch_bounds__(256) void prop(
    const float* __restrict__ vin, float* __restrict__ vout,
    float* __restrict__ res, const float* __restrict__ araw,
    const int* __restrict__ tki, const float* __restrict__ tkp,
    const int* __restrict__ tkc, int iter)
{
    const int row = blockIdx.x * 4 + (threadIdx.x >> 6);
    const int lane = threadIdx.x & 63;
    const int bh = row >> 11;
    const int h = bh & 15;
    const int cnt = tkc[row];
    const int* idx = tki + (size_t)row * CAP;
    const float* pr = tkp + (size_t)row * CAP;
    const float* vb = vin + (size_t)bh * NSEQ * DHEAD;

    float a0 = 0.f, a1 = 0.f, a2 = 0.f, a3 = 0.f;
    int j = 0;
    for (; j + 4 <= cnt; j += 4) {
        int i0 = idx[j], i1 = idx[j + 1], i2 = idx[j + 2], i3 = idx[j + 3];
        float p0 = pr[j], p1 = pr[j + 1], p2 = pr[j + 2], p3 = pr[j + 3];
        a0 += p0 * vb[(size_t)i0 * DHEAD + lane];
        a1 += p1 * vb[(size_t)i1 * DHEAD + lane];
        a2 += p2 * vb[(size_t)i2 * DHEAD + lane];
        a3 += p3 * vb[(size_t)i3 * DHEAD + lane];
    }
    for (; j < cnt; j++) a0 += pr[j] * vb[(size_t)idx[j] * DHEAD + lane];
    float acc = (a0 + a1) + (a2 + a3);

    vout[(size_t)row * DHEAD + lane] = acc;

    float ar = araw[iter * HHEADS + h];
    float alpha = 1.f / (1.f + __expf(-ar));
    const int b = row >> 15, n = row & 2047;
    size_t ro = ((size_t)(b * NSEQ + n)) * 1024 + h * DHEAD + lane;
    if (iter == 1) res[ro] = alpha * acc;
    else           res[ro] += alpha * acc;
}

// ---------------------------------------------------------------------------
// Kernel 4: output GEMM.  res[4096,1024] @ Wout[1024,1024] + bout -> out
// ---------------------------------------------------------------------------
__global__ __launch_bounds__(256) void out_gemm(
    const float* __restrict__ A, const float* __restrict__ W,
    const float* __restrict__ bias, float* __restrict__ out)
{
    __shared__ float As[16][64];
    __shared__ float Bs[16][64];
    const int tid = threadIdx.x;
    const int rowBase = blockIdx.y * 64;
    const int colBase = blockIdx.x * 64;
    const int tx = tid & 15, ty = tid >> 4;
    const int aRow = tid >> 2, aCol = (tid & 3) << 2;
    const int bRow = tid >> 4, bCol = (tid & 15) << 2;

    float acc[4][4] = {};
    for (int k0 = 0; k0 < 1024; k0 += 16) {
        float4 av = *reinterpret_cast<const float4*>(&A[(size_t)(rowBase + aRow) * 1024 + k0 + aCol]);
        float4 bv = *reinterpret_cast<const float4*>(&W[(size_t)(k0 + bRow) * 1024 + colBase + bCol]);
        __syncthreads();
        As[aCol + 0][aRow] = av.x; As[aCol + 1][aRow] = av.y;
        As[aCol + 2][aRow] = av.z; As[aCol + 3][aRow] = av.w;
        *reinterpret_cast<float4*>(&Bs[bRow][bCol]) = bv;
        __syncthreads();
#pragma unroll
        for (int kk = 0; kk < 16; kk++) {
            float4 a4 = *reinterpret_cast<const float4*>(&As[kk][ty << 2]);
            float4 b4 = *reinterpret_cast<const float4*>(&Bs[kk][tx << 2]);
            float ar[4] = {a4.x, a4.y, a4.z, a4.w};
            float br[4] = {b4.x, b4.y, b4.z, b4.w};
#pragma unroll
            for (int i = 0; i < 4; i++)
#pragma unroll
                for (int j = 0; j < 4; j++) acc[i][j] += ar[i] * br[j];
        }
    }
    float4 bb = *reinterpret_cast<const float4*>(&bias[colBase + (tx << 2)]);
#pragma unroll
    for (int i = 0; i < 4; i++) {
        int r = rowBase + (ty << 2) + i;
        float4 st;
        st.x = acc[i][0] + bb.x; st.y = acc[i][1] + bb.y;
        st.z = acc[i][2] + bb.z; st.w = acc[i][3] + bb.w;
        *reinterpret_cast<float4*>(&out[(size_t)r * 1024 + colBase + (tx << 2)]) = st;
    }
}

// ---------------------------------------------------------------------------
extern "C" void kernel_launch(void* const* d_in, const int* in_sizes, int n_in,
                              void* d_out, int out_size, void* d_ws, size_t ws_size,
                              hipStream_t stream)
{
    const float* x    = (const float*)d_in[0];
    const float* Wqkv = (const float*)d_in[1];
    const float* bqkv = (const float*)d_in[2];
    const float* Wout = (const float*)d_in[3];
    const float* bout = (const float*)d_in[4];
    const float* araw = (const float*)d_in[5];
    float* out = (float*)d_out;

    const size_t SEG = (size_t)1 << 22;   // 4M floats = one [B,H,N,DH] tensor
    float* ws = (float*)d_ws;
    float* q   = ws;                // [0, 4M)
    float* k   = q + SEG;           // [4M, 8M)
    float* v   = k + SEG;           // [8M, 12M)
    float* vA  = v + SEG;           // [12M, 16M)
    int*   tki = (int*)(vA + SEG);                  // 65536*68 ints
    float* tkp = (float*)(tki + (size_t)NROWS * CAP);
    int*   tkc = (int*)(tkp + (size_t)NROWS * CAP);
    uint32_t* keyg = (uint32_t*)(tkc + NROWS);      // 65536*2048 u32 = 512 MB
    float* res = q;                 // q is dead after scores; alias

    const size_t keyg_off   = (size_t)((char*)keyg - (char*)d_ws);
    const size_t need_bytes = keyg_off + (size_t)NROWS * 2048 * sizeof(uint32_t);

    qkv_gemm<<<dim3(48, 64), 256, 0, stream>>>(x, Wqkv, bqkv, q, k, v);

    if (ws_size >= need_bytes) {
        scores_kernel<<<dim3(128, 32), 256, 0, stream>>>(q, k, keyg);
        topk_kernel<<<dim3(NROWS / 4), 256, 0, stream>>>(keyg, tki, tkp, tkc);
    } else {
        scores_topk<<<dim3(256, 32), 256, 0, stream>>>(q, k, tki, tkp, tkc);
    }

    prop<<<dim3(NROWS / 4), 256, 0, stream>>>(v,  vA, res, araw, tki, tkp, tkc, 1);
    prop<<<dim3(NROWS / 4), 256, 0, stream>>>(vA, v,  res, araw, tki, tkp, tkc, 2);
    prop<<<dim3(NROWS / 4), 256, 0, stream>>>(v,  vA, res, araw, tki, tkp, tkc, 3);
    out_gemm<<<dim3(16, 64), 256, 0, stream>>>(res, Wout, bout, out);
}

// Round 6
// 1518.734 us; speedup vs baseline: 11.1071x; 1.5654x over previous
//
#include <hip/hip_runtime.h>
#include <cstdint>
#include <cstddef>

#define HHEADS 16
#define DHEAD  64
#define NSEQ   2048
#define NBATCH 2
#define NDIM   1024
#define TOPKN  64
#define CAP    68
#define NROWS  (NBATCH*HHEADS*NSEQ)   // 65536

// ---------------------------------------------------------------------------
// Kernel 1: QKV GEMM.  x[4096,1024] @ Wqkv[1024,3072] + bqkv
// -> q,k,v each laid out [B,H,N,DH]
// ---------------------------------------------------------------------------
__global__ __launch_bounds__(256) void qkv_gemm(
    const float* __restrict__ x, const float* __restrict__ W,
    const float* __restrict__ bias,
    float* __restrict__ qout, float* __restrict__ kout, float* __restrict__ vout)
{
    __shared__ float As[16][64];   // transposed A tile
    __shared__ float Bs[16][64];
    const int tid = threadIdx.x;
    const int rowBase = blockIdx.y * 64;
    const int colBase = blockIdx.x * 64;
    const int tx = tid & 15, ty = tid >> 4;
    const int aRow = tid >> 2, aCol = (tid & 3) << 2;
    const int bRow = tid >> 4, bCol = (tid & 15) << 2;

    float acc[4][4] = {};
    for (int k0 = 0; k0 < NDIM; k0 += 16) {
        float4 av = *reinterpret_cast<const float4*>(&x[(size_t)(rowBase + aRow) * NDIM + k0 + aCol]);
        float4 bv = *reinterpret_cast<const float4*>(&W[(size_t)(k0 + bRow) * 3072 + colBase + bCol]);
        __syncthreads();
        As[aCol + 0][aRow] = av.x; As[aCol + 1][aRow] = av.y;
        As[aCol + 2][aRow] = av.z; As[aCol + 3][aRow] = av.w;
        *reinterpret_cast<float4*>(&Bs[bRow][bCol]) = bv;
        __syncthreads();
#pragma unroll
        for (int kk = 0; kk < 16; kk++) {
            float4 a4 = *reinterpret_cast<const float4*>(&As[kk][ty << 2]);
            float4 b4 = *reinterpret_cast<const float4*>(&Bs[kk][tx << 2]);
            float ar[4] = {a4.x, a4.y, a4.z, a4.w};
            float br[4] = {b4.x, b4.y, b4.z, b4.w};
#pragma unroll
            for (int i = 0; i < 4; i++)
#pragma unroll
                for (int j = 0; j < 4; j++) acc[i][j] += ar[i] * br[j];
        }
    }
    const int which = colBase >> 10;
    const int h = (colBase & 1023) >> 6;
    float* dst = which == 0 ? qout : (which == 1 ? kout : vout);
    const int d0 = (colBase + (tx << 2)) & 63;
    float4 bb = *reinterpret_cast<const float4*>(&bias[colBase + (tx << 2)]);
#pragma unroll
    for (int i = 0; i < 4; i++) {
        int r = rowBase + (ty << 2) + i;
        int b = r >> 11, n = r & 2047;
        size_t o = ((size_t)((b << 4) + h) * NSEQ + n) * DHEAD + d0;
        float4 st;
        st.x = acc[i][0] + bb.x; st.y = acc[i][1] + bb.y;
        st.z = acc[i][2] + bb.z; st.w = acc[i][3] + bb.w;
        *reinterpret_cast<float4*>(&dst[o]) = st;
    }
}

// ---------------------------------------------------------------------------
// order-preserving float<->uint key transforms
// ---------------------------------------------------------------------------
__device__ __forceinline__ uint32_t f2key(float f) {
    uint32_t u = __float_as_uint(f);
    return (u & 0x80000000u) ? ~u : (u | 0x80000000u);
}
__device__ __forceinline__ float key2f(uint32_t k) {
    uint32_t u = (k & 0x80000000u) ? (k & 0x7FFFFFFFu) : ~k;
    return __uint_as_float(u);
}

// Per-row top-64 + softmax + compacted emit, entirely from 32 key registers.
// k[t] holds key of score j = (t>>2)*256 + lane*4 + (t&3).
__device__ __forceinline__ void topk_emit(
    uint32_t (&k)[32], float m, int row, int lane,
    int* __restrict__ tki, float* __restrict__ tkp, int* __restrict__ tkc)
{
    // bisection for the 64th-largest key (ballot count, wave-uniform scalar)
    uint32_t lo = 0u, hi = 0xFFFFFFFFu;
    while (lo < hi) {
        uint32_t mid = (uint32_t)(((uint64_t)lo + (uint64_t)hi + 1ull) >> 1);
        int c = 0;
#pragma unroll
        for (int t = 0; t < 32; t++)
            c += (int)__popcll(__ballot(k[t] >= mid));
        if (c >= TOPKN) { lo = mid; if (c == TOPKN) { hi = mid; } }
        else hi = mid - 1;
    }
    const uint32_t thr = lo;

    // softmax over kept entries (overwrite k[t] with exp bits; keep mask)
    uint32_t keep = 0;
    float sum = 0.f;
#pragma unroll
    for (int t = 0; t < 32; t++) {
        bool kp = (k[t] >= thr);
        float e = kp ? __expf(key2f(k[t]) - m) : 0.f;
        k[t] = __float_as_uint(e);
        sum += e;
        keep |= kp ? (1u << t) : 0u;
    }
#pragma unroll
    for (int off = 32; off >= 1; off >>= 1) sum += __shfl_xor(sum, off);
    const float rs = 1.f / sum;

    // compacted emit
    int base = 0;
    const unsigned long long below = (1ull << lane) - 1ull;
#pragma unroll
    for (int t = 0; t < 32; t++) {
        bool kp = (keep >> t) & 1u;
        unsigned long long mask = __ballot(kp);
        if (kp) {
            int pos = base + (int)__popcll(mask & below);
            if (pos < CAP) {
                tki[(size_t)row * CAP + pos] = ((t >> 2) << 8) + (lane << 2) + (t & 3);
                tkp[(size_t)row * CAP + pos] = __uint_as_float(k[t]) * rs;
            }
        }
        base += (int)__popcll(mask);
    }
    if (lane == 0) tkc[row] = base < CAP ? base : CAP;
}

// direct global->LDS 16B copy (no VGPR round-trip). lds base must be
// wave-uniform; HW scatters lane i to base + i*16 (m104/m108).
__device__ __forceinline__ void gload_lds16(const void* g, void* l) {
    __builtin_amdgcn_global_load_lds(
        (const __attribute__((address_space(1))) unsigned int*)g,
        (__attribute__((address_space(3))) unsigned int*)l,
        16, 0, 0);
}

// ---------------------------------------------------------------------------
// Kernel 2a: scores for query range [n0, n0+Nc) of every (b,h).
// Block = 4 waves, 4 rows/wave (16 rows/block) -> K LDS-read traffic
// amortized 4x.  Keys stream to global keyg[bh*Nc + (n-n0)][2048].
// LDS = 68 KB -> 2 blocks/CU.
// ---------------------------------------------------------------------------
__global__ __launch_bounds__(256) void scores_kernel(
    const float* __restrict__ qg, const float* __restrict__ kg,
    uint32_t* __restrict__ keyg, int n0, int Nc)
{
    __shared__ float4 Ks[2][2048];   // 64 KB (2 x 128 keys x 16 chunks, swizzled)
    __shared__ float  qs[16][64];    // 4 KB
    const int bh = blockIdx.y;
    const int wave = threadIdx.x >> 6, lane = threadIdx.x & 63;
    const size_t kbase = (size_t)bh * NSEQ * DHEAD;

    // stage the block's 16 q rows (all 256 threads, one float4 each)
    {
        int r = threadIdx.x >> 4, c4 = threadIdx.x & 15;
        *reinterpret_cast<float4*>(&qs[r][c4 << 2]) =
            *reinterpret_cast<const float4*>(
                &qg[((size_t)bh * NSEQ + n0 + blockIdx.x * 16 + r) * DHEAD + (c4 << 2)]);
    }

    // staging geometry: chunk = rep*256 + wave*64 + lane (linear LDS dest);
    // j = chunk>>4 = rep*16 + wave*4 + (lane>>4); swz = lane&15; c = swz^(j&7)
    const int jw  = wave * 4 + (lane >> 4);
    const int swz = lane & 15;
    auto stage = [&](int T, int buf) {
#pragma unroll
        for (int rep = 0; rep < 8; rep++) {
            int j = rep * 16 + jw;
            int c = swz ^ (j & 7);
            gload_lds16(&kg[kbase + (size_t)(T * 128 + j) * DHEAD + (c << 2)],
                        (char*)&Ks[buf][0] + (rep * 4096 + wave * 1024));
        }
    };

    stage(0, 0);
    __syncthreads();   // tile 0 staged (and qs visible)

    const int rA = wave * 4;
    const size_t rloc = (size_t)bh * Nc + blockIdx.x * 16 + rA;   // chunk-local row

    for (int KT = 0; KT < 16; KT++) {
        const int cur = KT & 1;
        if (KT < 15) stage(KT + 1, cur ^ 1);   // issue-early; drained at barrier

        float acc[4][2];
#pragma unroll
        for (int r = 0; r < 4; r++) { acc[r][0] = 0.f; acc[r][1] = 0.f; }

#pragma unroll
        for (int c = 0; c < 16; c++) {
            int j0 = lane, j1 = 64 + lane;
            float4 kv0 = Ks[cur][(j0 << 4) + (c ^ (j0 & 7))];
            float4 kv1 = Ks[cur][(j1 << 4) + (c ^ (j1 & 7))];
#pragma unroll
            for (int r = 0; r < 4; r++) {
                // q reads are same-address broadcasts (no bank conflict)
                float4 qr = *reinterpret_cast<const float4*>(&qs[rA + r][c << 2]);
                acc[r][0] += qr.x * kv0.x + qr.y * kv0.y + qr.z * kv0.z + qr.w * kv0.w;
                acc[r][1] += qr.x * kv1.x + qr.y * kv1.y + qr.z * kv1.z + qr.w * kv1.w;
            }
        }
        // finalize this tile's 8 scores: scale, key-encode, stream to global
#pragma unroll
        for (int r = 0; r < 4; r++) {
            size_t ro = (rloc + r) * 2048 + KT * 128;
            keyg[ro + lane]      = f2key(acc[r][0] * 0.125f);
            keyg[ro + 64 + lane] = f2key(acc[r][1] * 0.125f);
        }
        __syncthreads();   // drains staging vmcnt; all waves done with Ks[cur]
    }
}

// ---------------------------------------------------------------------------
// Kernel 2b: top-k + softmax from keyg chunk.  1 wave per row, no LDS ->
// high occupancy hides the bisection's serial chain and the key reload.
// Row max recovered exactly from keys (order-preserving transform).
// ---------------------------------------------------------------------------
__global__ __launch_bounds__(256) void topk_kernel(
    const uint32_t* __restrict__ keyg,
    int* __restrict__ tki, float* __restrict__ tkp, int* __restrict__ tkc,
    int n0, int lgNc)
{
    const int rloc = blockIdx.x * 4 + (threadIdx.x >> 6);
    const int lane = threadIdx.x & 63;
    const int bh = rloc >> lgNc;
    const int n  = n0 + (rloc & ((1 << lgNc) - 1));
    const int row = (bh << 11) + n;
    const uint4* src = reinterpret_cast<const uint4*>(keyg + (size_t)rloc * 2048);

    uint32_t k[32];
#pragma unroll
    for (int p = 0; p < 8; p++) {
        uint4 c4 = src[p * 64 + lane];
        k[p * 4 + 0] = c4.x; k[p * 4 + 1] = c4.y;
        k[p * 4 + 2] = c4.z; k[p * 4 + 3] = c4.w;
    }
    uint32_t km = 0;
#pragma unroll
    for (int t = 0; t < 32; t++) km = k[t] > km ? k[t] : km;
#pragma unroll
    for (int off = 32; off >= 1; off >>= 1) {
        uint32_t o = __shfl_xor(km, off);
        km = o > km ? o : km;
    }
    topk_emit(k, key2f(km), row, lane, tki, tkp, tkc);
}

// ---------------------------------------------------------------------------
// Kernel 2 (fallback, fused): scores + top-k via LDS key bounce (R4 design).
// Unreachable given ws_size >= 100 MB, kept for safety.
// ---------------------------------------------------------------------------
__global__ __launch_bounds__(256) void scores_topk(
    const float* __restrict__ qg, const float* __restrict__ kg,
    int* __restrict__ tki, float* __restrict__ tkp, int* __restrict__ tkc)
{
    __shared__ float4   Ks[2][2048];
    __shared__ float    qs[8][64];
    __shared__ uint32_t keyk[8][2048];
    const int bh = blockIdx.y;
    const int wave = threadIdx.x >> 6, lane = threadIdx.x & 63;
    const size_t kbase = (size_t)bh * NSEQ * DHEAD;

    if (threadIdx.x < 128) {
        int r = threadIdx.x >> 4, c4 = threadIdx.x & 15;
        *reinterpret_cast<float4*>(&qs[r][c4 << 2]) =
            *reinterpret_cast<const float4*>(
                &qg[((size_t)bh * NSEQ + blockIdx.x * 8 + r) * DHEAD + (c4 << 2)]);
    }

    const int jw  = wave * 4 + (lane >> 4);
    const int swz = lane & 15;
    auto stage = [&](int T, int buf) {
#pragma unroll
        for (int rep = 0; rep < 8; rep++) {
            int j = rep * 16 + jw;
            int c = swz ^ (j & 7);
            gload_lds16(&kg[kbase + (size_t)(T * 128 + j) * DHEAD + (c << 2)],
                        (char*)&Ks[buf][0] + (rep * 4096 + wave * 1024));
        }
    };

    stage(0, 0);
    __syncthreads();

    const int rA = wave * 2, rB = rA + 1;
    float mA = -3.4e38f, mB = -3.4e38f;

    for (int KT = 0; KT < 16; KT++) {
        const int cur = KT & 1;
        if (KT < 15) stage(KT + 1, cur ^ 1);

        float sA0 = 0.f, sA1 = 0.f, sB0 = 0.f, sB1 = 0.f;
#pragma unroll
        for (int c = 0; c < 16; c++) {
            float4 qa = *reinterpret_cast<const float4*>(&qs[rA][c << 2]);
            float4 qb = *reinterpret_cast<const float4*>(&qs[rB][c << 2]);
            int j0 = lane, j1 = 64 + lane;
            float4 kv0 = Ks[cur][(j0 << 4) + (c ^ (j0 & 7))];
            float4 kv1 = Ks[cur][(j1 << 4) + (c ^ (j1 & 7))];
            sA0 += qa.x * kv0.x + qa.y * kv0.y + qa.z * kv0.z + qa.w * kv0.w;
            sA1 += qa.x * kv1.x + qa.y * kv1.y + qa.z * kv1.z + qa.w * kv1.w;
            sB0 += qb.x * kv0.x + qb.y * kv0.y + qb.z * kv0.z + qb.w * kv0.w;
            sB1 += qb.x * kv1.x + qb.y * kv1.y + qb.z * kv1.z + qb.w * kv1.w;
        }
        sA0 *= 0.125f; sA1 *= 0.125f; sB0 *= 0.125f; sB1 *= 0.125f;
        mA = fmaxf(mA, fmaxf(sA0, sA1));
        mB = fmaxf(mB, fmaxf(sB0, sB1));
        keyk[rA][KT * 128 + lane]      = f2key(sA0);
        keyk[rA][KT * 128 + 64 + lane] = f2key(sA1);
        keyk[rB][KT * 128 + lane]      = f2key(sB0);
        keyk[rB][KT * 128 + 64 + lane] = f2key(sB1);
        __syncthreads();
    }

#pragma unroll
    for (int off = 32; off >= 1; off >>= 1) {
        mA = fmaxf(mA, __shfl_xor(mA, off));
        mB = fmaxf(mB, __shfl_xor(mB, off));
    }

    const int rowA = bh * NSEQ + blockIdx.x * 8 + wave * 2;
    {
        const uint4* src = reinterpret_cast<const uint4*>(&keyk[rA][0]);
        uint32_t k[32];
#pragma unroll
        for (int p = 0; p < 8; p++) {
            uint4 c4 = src[p * 64 + lane];
            k[p * 4 + 0] = c4.x; k[p * 4 + 1] = c4.y;
            k[p * 4 + 2] = c4.z; k[p * 4 + 3] = c4.w;
        }
        topk_emit(k, mA, rowA, lane, tki, tkp, tkc);
    }
    {
        const uint4* src = reinterpret_cast<const uint4*>(&keyk[rB][0]);
        uint32_t k[32];
#pragma unroll
        for (int p = 0; p < 8; p++) {
            uint4 c4 = src[p * 64 + lane];
            k[p * 4 + 0] = c4.x; k[p * 4 + 1] = c4.y;
            k[p * 4 + 2] = c4.z; k[p * 4 + 3] = c4.w;
        }
        topk_emit(k, mB, rowA + 1, lane, tki, tkp, tkc);
    }
}

// ---------------------------------------------------------------------------
// Kernel 3: one propagation step.  v_out[n] = sum_j p[n,j] * v_in[idx[n,j]];
// res(+)= sigmoid(alphas_raw[iter,h]) * v_out, res in [B,N,H*DH] layout.
// ---------------------------------------------------------------------------
__global__ __launch_bounds__(256) void prop(
    const float* __restrict__ vin, float* __restrict__ vout,
    float* __restrict__ res, const float* __restrict__ araw,
    const int* __restrict__ tki, const float* __restrict__ tkp,
    const int* __restrict__ tkc, int iter)
{
    const int row = blockIdx.x * 4 + (threadIdx.x >> 6);
    const int lane = threadIdx.x & 63;
    const int bh = row >> 11;
    const int h = bh & 15;
    const int cnt = tkc[row];
    const int* idx = tki + (size_t)row * CAP;
    const float* pr = tkp + (size_t)row * CAP;
    const float* vb = vin + (size_t)bh * NSEQ * DHEAD;

    float a0 = 0.f, a1 = 0.f, a2 = 0.f, a3 = 0.f;
    int j = 0;
    for (; j + 4 <= cnt; j += 4) {
        int i0 = idx[j], i1 = idx[j + 1], i2 = idx[j + 2], i3 = idx[j + 3];
        float p0 = pr[j], p1 = pr[j + 1], p2 = pr[j + 2], p3 = pr[j + 3];
        a0 += p0 * vb[(size_t)i0 * DHEAD + lane];
        a1 += p1 * vb[(size_t)i1 * DHEAD + lane];
        a2 += p2 * vb[(size_t)i2 * DHEAD + lane];
        a3 += p3 * vb[(size_t)i3 * DHEAD + lane];
    }
    for (; j < cnt; j++) a0 += pr[j] * vb[(size_t)idx[j] * DHEAD + lane];
    float acc = (a0 + a1) + (a2 + a3);

    vout[(size_t)row * DHEAD + lane] = acc;

    float ar = araw[iter * HHEADS + h];
    float alpha = 1.f / (1.f + __expf(-ar));
    const int b = row >> 15, n = row & 2047;
    size_t ro = ((size_t)(b * NSEQ + n)) * 1024 + h * DHEAD + lane;
    if (iter == 1) res[ro] = alpha * acc;
    else           res[ro] += alpha * acc;
}

// ---------------------------------------------------------------------------
// Kernel 4: output GEMM.  res[4096,1024] @ Wout[1024,1024] + bout -> out
// ---------------------------------------------------------------------------
__global__ __launch_bounds__(256) void out_gemm(
    const float* __restrict__ A, const float* __restrict__ W,
    const float* __restrict__ bias, float* __restrict__ out)
{
    __shared__ float As[16][64];
    __shared__ float Bs[16][64];
    const int tid = threadIdx.x;
    const int rowBase = blockIdx.y * 64;
    const int colBase = blockIdx.x * 64;
    const int tx = tid & 15, ty = tid >> 4;
    const int aRow = tid >> 2, aCol = (tid & 3) << 2;
    const int bRow = tid >> 4, bCol = (tid & 15) << 2;

    float acc[4][4] = {};
    for (int k0 = 0; k0 < 1024; k0 += 16) {
        float4 av = *reinterpret_cast<const float4*>(&A[(size_t)(rowBase + aRow) * 1024 + k0 + aCol]);
        float4 bv = *reinterpret_cast<const float4*>(&W[(size_t)(k0 + bRow) * 1024 + colBase + bCol]);
        __syncthreads();
        As[aCol + 0][aRow] = av.x; As[aCol + 1][aRow] = av.y;
        As[aCol + 2][aRow] = av.z; As[aCol + 3][aRow] = av.w;
        *reinterpret_cast<float4*>(&Bs[bRow][bCol]) = bv;
        __syncthreads();
#pragma unroll
        for (int kk = 0; kk < 16; kk++) {
            float4 a4 = *reinterpret_cast<const float4*>(&As[kk][ty << 2]);
            float4 b4 = *reinterpret_cast<const float4*>(&Bs[kk][tx << 2]);
            float ar[4] = {a4.x, a4.y, a4.z, a4.w};
            float br[4] = {b4.x, b4.y, b4.z, b4.w};
#pragma unroll
            for (int i = 0; i < 4; i++)
#pragma unroll
                for (int j = 0; j < 4; j++) acc[i][j] += ar[i] * br[j];
        }
    }
    float4 bb = *reinterpret_cast<const float4*>(&bias[colBase + (tx << 2)]);
#pragma unroll
    for (int i = 0; i < 4; i++) {
        int r = rowBase + (ty << 2) + i;
        float4 st;
        st.x = acc[i][0] + bb.x; st.y = acc[i][1] + bb.y;
        st.z = acc[i][2] + bb.z; st.w = acc[i][3] + bb.w;
        *reinterpret_cast<float4*>(&out[(size_t)r * 1024 + colBase + (tx << 2)]) = st;
    }
}

// ---------------------------------------------------------------------------
extern "C" void kernel_launch(void* const* d_in, const int* in_sizes, int n_in,
                              void* d_out, int out_size, void* d_ws, size_t ws_size,
                              hipStream_t stream)
{
    const float* x    = (const float*)d_in[0];
    const float* Wqkv = (const float*)d_in[1];
    const float* bqkv = (const float*)d_in[2];
    const float* Wout = (const float*)d_in[3];
    const float* bout = (const float*)d_in[4];
    const float* araw = (const float*)d_in[5];
    float* out = (float*)d_out;

    const size_t SEG = (size_t)1 << 22;   // 4M floats = one [B,H,N,DH] tensor
    float* ws = (float*)d_ws;
    float* q   = ws;                // [0, 16MB)
    float* k   = q + SEG;           // [16, 32MB)
    float* v   = k + SEG;           // [32, 48MB)
    int*   tki = (int*)(v + SEG);                   // 65536*68 ints (17.8MB)
    float* tkp = (float*)(tki + (size_t)NROWS * CAP);
    int*   tkc = (int*)(tkp + (size_t)NROWS * CAP);
    uint32_t* keyg = (uint32_t*)(tkc + NROWS);      // chunked key scratch
    float* vA  = (float*)keyg;      // keyg dead before prop1; alias (16MB)
    float* res = q;                 // q dead after scores; alias

    const size_t keyg_off = (size_t)((char*)keyg - (char*)d_ws);
    const size_t leftover = ws_size > keyg_off ? ws_size - keyg_off : 0;

    // largest power-of-two Nc (query positions per chunk) whose keyg fits:
    // bytes(Nc) = 32 slices * Nc rows * 2048 keys * 4B = Nc << 18
    int Nc = NSEQ;
    while (Nc >= 64 && (((size_t)Nc) << 18) > leftover) Nc >>= 1;

    qkv_gemm<<<dim3(48, 64), 256, 0, stream>>>(x, Wqkv, bqkv, q, k, v);

    if (Nc >= 64) {
        int lgNc = __builtin_ctz((unsigned)Nc);
        for (int n0 = 0; n0 < NSEQ; n0 += Nc) {
            scores_kernel<<<dim3(Nc / 16, 32), 256, 0, stream>>>(q, k, keyg, n0, Nc);
            topk_kernel<<<dim3(32 * Nc / 4), 256, 0, stream>>>(keyg, tki, tkp, tkc, n0, lgNc);
        }
    } else {
        scores_topk<<<dim3(256, 32), 256, 0, stream>>>(q, k, tki, tkp, tkc);
    }

    prop<<<dim3(NROWS / 4), 256, 0, stream>>>(v,  vA, res, araw, tki, tkp, tkc, 1);
    prop<<<dim3(NROWS / 4), 256, 0, stream>>>(vA, v,  res, araw, tki, tkp, tkc, 2);
    prop<<<dim3(NROWS / 4), 256, 0, stream>>>(v,  vA, res, araw, tki, tkp, tkc, 3);
    out_gemm<<<dim3(16, 64), 256, 0, stream>>>(res, Wout, bout, out);
}